// Round 1
// baseline (53.895 us; speedup 1.0000x reference)
//
#include <hip/hip_runtime.h>

#define BATCH 16384
#define NFEAT 50
#define DIM   128

__global__ __launch_bounds__(256) void mf_dot_kernel(
    const int*   __restrict__ user_ids,
    const int*   __restrict__ item_ids,
    const int*   __restrict__ ufi,
    const float* __restrict__ ufv,
    const int*   __restrict__ ifi,
    const float* __restrict__ ifv,
    const float* __restrict__ user_emb,
    const float* __restrict__ item_emb,
    const float* __restrict__ user_feat_emb,
    const float* __restrict__ item_feat_emb,
    float*       __restrict__ out)
{
    const int lane = threadIdx.x & 63;
    const int wave = threadIdx.x >> 6;
    const int b = blockIdx.x * (blockDim.x >> 6) + wave;
    if (b >= BATCH) return;

    // Preload this element's 50 (index, value) pairs into lanes 0..49.
    int   uidx = 0, iidx = 0;
    float uval = 0.f, ival = 0.f;
    if (lane < NFEAT) {
        uidx = ufi[b * NFEAT + lane];
        uval = ufv[b * NFEAT + lane];
        iidx = ifi[b * NFEAT + lane];
        ival = ifv[b * NFEAT + lane];
    }

    const int d0 = lane * 2;  // each lane owns dims [d0, d0+1]

    const int uid = user_ids[b];
    const int iid = item_ids[b];

    float2 uacc = *reinterpret_cast<const float2*>(user_emb + (size_t)uid * DIM + d0);
    float2 vacc = *reinterpret_cast<const float2*>(item_emb + (size_t)iid * DIM + d0);

    #pragma unroll 10
    for (int f = 0; f < NFEAT; ++f) {
        const int   idx = __shfl(uidx, f);
        const float val = __shfl(uval, f);
        const float2 e = *reinterpret_cast<const float2*>(user_feat_emb + (size_t)idx * DIM + d0);
        uacc.x = fmaf(val, e.x, uacc.x);
        uacc.y = fmaf(val, e.y, uacc.y);
    }

    #pragma unroll 10
    for (int f = 0; f < NFEAT; ++f) {
        const int   idx = __shfl(iidx, f);
        const float val = __shfl(ival, f);
        const float2 e = *reinterpret_cast<const float2*>(item_feat_emb + (size_t)idx * DIM + d0);
        vacc.x = fmaf(val, e.x, vacc.x);
        vacc.y = fmaf(val, e.y, vacc.y);
    }

    float dot = uacc.x * vacc.x + uacc.y * vacc.y;

    // 64-lane butterfly reduction.
    #pragma unroll
    for (int off = 32; off > 0; off >>= 1)
        dot += __shfl_xor(dot, off);

    if (lane == 0) out[b] = dot;
}

extern "C" void kernel_launch(void* const* d_in, const int* in_sizes, int n_in,
                              void* d_out, int out_size, void* d_ws, size_t ws_size,
                              hipStream_t stream) {
    const int*   user_ids      = (const int*)  d_in[0];
    const int*   item_ids      = (const int*)  d_in[1];
    const int*   ufi           = (const int*)  d_in[2];
    const float* ufv           = (const float*)d_in[3];
    const int*   ifi           = (const int*)  d_in[4];
    const float* ifv           = (const float*)d_in[5];
    const float* user_emb      = (const float*)d_in[6];
    const float* item_emb      = (const float*)d_in[7];
    const float* user_feat_emb = (const float*)d_in[8];
    const float* item_feat_emb = (const float*)d_in[9];
    float* out = (float*)d_out;

    const int waves_per_block = 4;             // 256 threads
    const int grid = BATCH / waves_per_block;  // 4096 blocks
    mf_dot_kernel<<<grid, waves_per_block * 64, 0, stream>>>(
        user_ids, item_ids, ufi, ufv, ifi, ifv,
        user_emb, item_emb, user_feat_emb, item_feat_emb, out);
}

// Round 2
// 38.705 us; speedup vs baseline: 1.3925x; 1.3925x over previous
//
#include <hip/hip_runtime.h>

#define BATCH 16384
#define NFEAT 50
#define DIM   128

// One wave handles TWO batch elements: lanes 0-31 -> b0, lanes 32-63 -> b1.
// Each lane owns 4 dims (float4): 32 lanes x 16 B = one full 512 B row.
// Index/value reads are made wave-uniform (readfirstlane on the wave id) so
// the compiler lowers them to s_load through the scalar cache, keeping the
// vector-memory pipe exclusively for the embedding-row gathers.
__global__ __launch_bounds__(256) void mf_dot_kernel(
    const int*   __restrict__ user_ids,
    const int*   __restrict__ item_ids,
    const int*   __restrict__ ufi,
    const float* __restrict__ ufv,
    const int*   __restrict__ ifi,
    const float* __restrict__ ifv,
    const float* __restrict__ user_emb,
    const float* __restrict__ item_emb,
    const float* __restrict__ user_feat_emb,
    const float* __restrict__ item_feat_emb,
    float*       __restrict__ out)
{
    const int tid  = threadIdx.x;
    const int lane = tid & 63;
    const int half = lane >> 5;   // which batch element within the wave
    const int sl   = lane & 31;   // lane within the half-wave
    const int d0   = sl * 4;      // this lane's 4 dims

    // Global wave id, forced wave-uniform so dependent loads go scalar.
    int wv = (int)((blockIdx.x * blockDim.x + tid) >> 6);
    wv = __builtin_amdgcn_readfirstlane(wv);
    const int b0 = wv * 2;
    const int b1 = b0 + 1;
    const int b  = half ? b1 : b0;

    // Base id embeddings (ids are uniform scalars; row select per half).
    const int uid0 = user_ids[b0], uid1 = user_ids[b1];
    const int iid0 = item_ids[b0], iid1 = item_ids[b1];
    const int urow = half ? uid1 : uid0;
    const int irow = half ? iid1 : iid0;

    float4 uacc = *reinterpret_cast<const float4*>(user_emb + (size_t)urow * DIM + d0);
    float4 vacc = *reinterpret_cast<const float4*>(item_emb + (size_t)irow * DIM + d0);

    const int* __restrict__ ufi0 = ufi + (size_t)b0 * NFEAT;
    const int* __restrict__ ufi1 = ufi + (size_t)b1 * NFEAT;
    const float* __restrict__ ufv0 = ufv + (size_t)b0 * NFEAT;
    const float* __restrict__ ufv1 = ufv + (size_t)b1 * NFEAT;
    const int* __restrict__ ifi0 = ifi + (size_t)b0 * NFEAT;
    const int* __restrict__ ifi1 = ifi + (size_t)b1 * NFEAT;
    const float* __restrict__ ifv0 = ifv + (size_t)b0 * NFEAT;
    const float* __restrict__ ifv1 = ifv + (size_t)b1 * NFEAT;

    #pragma unroll 10
    for (int f = 0; f < NFEAT; ++f) {
        // Scalar loads (uniform addresses) -> s_load via constant cache.
        const int   ui0 = ufi0[f], ui1 = ufi1[f];
        const float uv0 = ufv0[f], uv1 = ufv1[f];
        const int   ii0 = ifi0[f], ii1 = ifi1[f];
        const float iv0 = ifv0[f], iv1 = ifv1[f];

        const int   ur = half ? ui1 : ui0;
        const float uw = half ? uv1 : uv0;
        const int   ir = half ? ii1 : ii0;
        const float iw = half ? iv1 : iv0;

        const float4 ue = *reinterpret_cast<const float4*>(user_feat_emb + (size_t)ur * DIM + d0);
        const float4 ie = *reinterpret_cast<const float4*>(item_feat_emb + (size_t)ir * DIM + d0);

        uacc.x = fmaf(uw, ue.x, uacc.x);
        uacc.y = fmaf(uw, ue.y, uacc.y);
        uacc.z = fmaf(uw, ue.z, uacc.z);
        uacc.w = fmaf(uw, ue.w, uacc.w);
        vacc.x = fmaf(iw, ie.x, vacc.x);
        vacc.y = fmaf(iw, ie.y, vacc.y);
        vacc.z = fmaf(iw, ie.z, vacc.z);
        vacc.w = fmaf(iw, ie.w, vacc.w);
    }

    float dot = uacc.x * vacc.x + uacc.y * vacc.y + uacc.z * vacc.z + uacc.w * vacc.w;

    // Reduce across the 32-lane half (offsets <=16 stay within the half).
    #pragma unroll
    for (int off = 16; off > 0; off >>= 1)
        dot += __shfl_xor(dot, off);

    if (sl == 0) out[b] = dot;
}

extern "C" void kernel_launch(void* const* d_in, const int* in_sizes, int n_in,
                              void* d_out, int out_size, void* d_ws, size_t ws_size,
                              hipStream_t stream) {
    const int*   user_ids      = (const int*)  d_in[0];
    const int*   item_ids      = (const int*)  d_in[1];
    const int*   ufi           = (const int*)  d_in[2];
    const float* ufv           = (const float*)d_in[3];
    const int*   ifi           = (const int*)  d_in[4];
    const float* ifv           = (const float*)d_in[5];
    const float* user_emb      = (const float*)d_in[6];
    const float* item_emb      = (const float*)d_in[7];
    const float* user_feat_emb = (const float*)d_in[8];
    const float* item_feat_emb = (const float*)d_in[9];
    float* out = (float*)d_out;

    // 2 elements per wave, 4 waves per block -> 8 elements/block.
    const int elems_per_block = 8;
    const int grid = BATCH / elems_per_block;  // 2048 blocks
    mf_dot_kernel<<<grid, 256, 0, stream>>>(
        user_ids, item_ids, ufi, ufv, ifi, ifv,
        user_emb, item_emb, user_feat_emb, item_feat_emb, out);
}